// Round 9
// baseline (20.059 us; speedup 1.0000x reference)
//
#include <hip/hip_runtime.h>
#include <math.h>

#define B_ 128
#define K_ 2048
#define TEMP_ 0.07f
#define EPS_ 1e-12f
#define NBLK_ 1024   // 128 i * 8 j-groups

// Packed fp32 (CDNA dual-FP32): one instr = 2 fp32 ops/lane.
typedef float pf2 __attribute__((ext_vector_type(2)));

__device__ __forceinline__ pf2 pk_mul(pf2 a, pf2 b) {
    pf2 d;
    asm("v_pk_mul_f32 %0, %1, %2" : "=v"(d) : "v"(a), "v"(b));
    return d;
}
__device__ __forceinline__ pf2 pk_fma(pf2 a, pf2 b, pf2 c) {
    pf2 d;
    asm("v_pk_fma_f32 %0, %1, %2, %3" : "=v"(d) : "v"(a), "v"(b), "v"(c));
    return d;
}

// ---------------------------------------------------------------------------
// k_pairs v9: v8 minus the g LDS array.
//   w = b*(1+a^3) = fma(a^2, a*b, b)  -- p = a*b already needed for v-path,
// so g's ds_read_b128 (half of pass-2 DS traffic) becomes 1 packed mul.
// LDS: only a (8 KB). 16-lane group per j, two-pass direct v-form.
//
//   a = x_i/||x_i|| (LDS);  c = 1/max(||b||,eps)            [pass 1]
//   p = a*b; a2 = a*a; w = fma(a2,p,b): du=S(aw), uu=S(w^2)
//   q = p^2; v = fma(c,q,b):            dv=S(av), vv=S(v^2) [pass 2]
//   ds = du/max(sqrt(uu),eps)/T;  dn = dv/max(sqrt(vv),eps)/T
// Partials per (i,jg): sum_j ds, sum_j (e^ds + 3 e^dn).
// ---------------------------------------------------------------------------
__global__ __launch_bounds__(256, 4) void k_pairs(const float* __restrict__ feat,
                                                  float* __restrict__ part) {
    const int blk = blockIdx.x;
    const int i = blk >> 3;
    const int jg = blk & 7;
    const int tid = threadIdx.x;
    const int wave = tid >> 6, lane = tid & 63;
    const int s = lane & 15;      // sublane within 16-lane group
    const int grp = lane >> 4;    // group 0..3 -> which j

    __shared__ float sa[K_];
    __shared__ float wsum[4];

    // ---- stage i-row: block-local norm, then a into LDS ----
    {
        const float4* fi4 = reinterpret_cast<const float4*>(feat + (size_t)i * K_);
        float4 v0 = fi4[tid];
        float4 v1 = fi4[tid + 256];
        float ss = v0.x * v0.x + v0.y * v0.y + v0.z * v0.z + v0.w * v0.w
                 + v1.x * v1.x + v1.y * v1.y + v1.z * v1.z + v1.w * v1.w;
#pragma unroll
        for (int o = 1; o < 64; o <<= 1) ss += __shfl_xor(ss, o, 64);
        if (lane == 0) wsum[wave] = ss;
        __syncthreads();
        const float tot = wsum[0] + wsum[1] + wsum[2] + wsum[3];
        const float rn = 1.0f / fmaxf(sqrtf(tot), EPS_);

        float4* a4w = reinterpret_cast<float4*>(sa);
        float4 a0, a1;
        a0.x = v0.x * rn; a0.y = v0.y * rn; a0.z = v0.z * rn; a0.w = v0.w * rn;
        a1.x = v1.x * rn; a1.y = v1.y * rn; a1.z = v1.z * rn; a1.w = v1.w * rn;
        a4w[tid] = a0;
        a4w[tid + 256] = a1;
    }
    __syncthreads();

    const int j = jg * 16 + wave * 4 + grp;
    const float4* bj = reinterpret_cast<const float4*>(feat + (size_t)j * K_);
    const float4* a4 = reinterpret_cast<const float4*>(sa);

    // ---- pass 1: sbb (packed) ----
    pf2 sbb2 = {0.f, 0.f};
#pragma unroll 8
    for (int c = 0; c < 32; ++c) {
        const float4 b = bj[c * 16 + s];
        pf2 b01; b01.x = b.x; b01.y = b.y;
        pf2 b23; b23.x = b.z; b23.y = b.w;
        sbb2 = pk_fma(b01, b01, sbb2);
        sbb2 = pk_fma(b23, b23, sbb2);
    }
    float sbb = sbb2.x + sbb2.y;
#pragma unroll
    for (int o = 1; o < 16; o <<= 1) sbb += __shfl_xor(sbb, o, 64);
    const float cc = 1.0f / fmaxf(sqrtf(sbb), EPS_);
    pf2 cc2; cc2.x = cc; cc2.y = cc;

    // ---- pass 2: du, uu, dv, vv (packed; g-free w, direct v) ----
    pf2 du01 = {0.f, 0.f}, du23 = {0.f, 0.f};
    pf2 uu01 = {0.f, 0.f}, uu23 = {0.f, 0.f};
    pf2 dv01 = {0.f, 0.f}, dv23 = {0.f, 0.f};
    pf2 vv01 = {0.f, 0.f}, vv23 = {0.f, 0.f};
#pragma unroll 8
    for (int c = 0; c < 32; ++c) {
        const int idx = c * 16 + s;        // same for all 4 groups: LDS broadcast
        const float4 a = a4[idx];
        const float4 b = bj[idx];
        pf2 a01; a01.x = a.x; a01.y = a.y;
        pf2 a23; a23.x = a.z; a23.y = a.w;
        pf2 b01; b01.x = b.x; b01.y = b.y;
        pf2 b23; b23.x = b.z; b23.y = b.w;

        const pf2 p01 = pk_mul(a01, b01);
        const pf2 p23 = pk_mul(a23, b23);
        const pf2 s01 = pk_mul(a01, a01);     // a^2
        const pf2 s23 = pk_mul(a23, a23);
        const pf2 w01 = pk_fma(s01, p01, b01);  // b*(1+a^3)
        const pf2 w23 = pk_fma(s23, p23, b23);
        du01 = pk_fma(a01, w01, du01);
        du23 = pk_fma(a23, w23, du23);
        uu01 = pk_fma(w01, w01, uu01);
        uu23 = pk_fma(w23, w23, uu23);
        const pf2 q01 = pk_mul(p01, p01);
        const pf2 q23 = pk_mul(p23, p23);
        const pf2 v01 = pk_fma(cc2, q01, b01);
        const pf2 v23 = pk_fma(cc2, q23, b23);
        dv01 = pk_fma(a01, v01, dv01);
        dv23 = pk_fma(a23, v23, dv23);
        vv01 = pk_fma(v01, v01, vv01);
        vv23 = pk_fma(v23, v23, vv23);
    }
    float du = (du01.x + du01.y) + (du23.x + du23.y);
    float uu = (uu01.x + uu01.y) + (uu23.x + uu23.y);
    float dv = (dv01.x + dv01.y) + (dv23.x + dv23.y);
    float vv = (vv01.x + vv01.y) + (vv23.x + vv23.y);

    // ---- 4-step butterfly within the 16-lane group (4 sums) ----
#pragma unroll
    for (int o = 1; o < 16; o <<= 1) {
        du += __shfl_xor(du, o, 64);
        uu += __shfl_xor(uu, o, 64);
        dv += __shfl_xor(dv, o, 64);
        vv += __shfl_xor(vv, o, 64);
    }

    // ---- per-j epilogue ----
    const float inv_t = 1.0f / TEMP_;
    const float ds = du / fmaxf(sqrtf(uu), EPS_) * inv_t;
    const float dn = dv / fmaxf(sqrtf(vv), EPS_) * inv_t;
    float s1 = ds;
    float s2 = __expf(ds) + 3.0f * __expf(dn);

    // ---- combine the wave's 4 j's (cross-group butterfly) ----
    s1 += __shfl_xor(s1, 16, 64); s1 += __shfl_xor(s1, 32, 64);
    s2 += __shfl_xor(s2, 16, 64); s2 += __shfl_xor(s2, 32, 64);

    __shared__ float p1[4], p2[4];
    if (lane == 0) { p1[wave] = s1; p2[wave] = s2; }
    __syncthreads();
    if (tid == 0) {
        part[blk * 2 + 0] = p1[0] + p1[1] + p1[2] + p1[3];
        part[blk * 2 + 1] = p2[0] + p2[1] + p2[2] + p2[3];
    }
}

// ---------------------------------------------------------------------------
// k_final: thread i combines its 8 group-partials, computes
// contrib_i = (1/B) * sum_j d_self - log(denom_i), reduces over i.
// ---------------------------------------------------------------------------
__global__ __launch_bounds__(128) void k_final(const float* __restrict__ part,
                                               float* __restrict__ out) {
    const int i = threadIdx.x;
    float s1 = 0.0f, s2 = 0.0f;
#pragma unroll
    for (int q = 0; q < 8; ++q) {
        s1 += part[(i * 8 + q) * 2 + 0];
        s2 += part[(i * 8 + q) * 2 + 1];
    }
    float c = s1 * (1.0f / B_) - __logf(s2);
#pragma unroll
    for (int o = 1; o < 64; o <<= 1) c += __shfl_xor(c, o, 64);
    __shared__ float wsum[2];
    const int wave = i >> 6, lane = i & 63;
    if (lane == 0) wsum[wave] = c;
    __syncthreads();
    if (i == 0) out[0] = -(wsum[0] + wsum[1]) * (1.0f / B_);
}

extern "C" void kernel_launch(void* const* d_in, const int* in_sizes, int n_in,
                              void* d_out, int out_size, void* d_ws, size_t ws_size,
                              hipStream_t stream) {
    const float* feat = (const float*)d_in[0];
    float* part = (float*)d_ws;              // 1024*2 floats
    float* out = (float*)d_out;

    k_pairs<<<NBLK_, 256, 0, stream>>>(feat, part);
    k_final<<<1, 128, 0, stream>>>(part, out);
}

// Round 10
// 19.717 us; speedup vs baseline: 1.0173x; 1.0173x over previous
//
#include <hip/hip_runtime.h>
#include <math.h>

#define B_ 128
#define K_ 2048
#define TEMP_ 0.07f
#define EPS_ 1e-12f
#define NBLK_ 1024   // 128 i * 8 j-groups

// Packed fp32 (CDNA2+ dual-FP32): one instr = 2 fp32 ops/lane.
typedef float pf2 __attribute__((ext_vector_type(2)));

__device__ __forceinline__ pf2 pk_mul(pf2 a, pf2 b) {
    pf2 d;
    asm("v_pk_mul_f32 %0, %1, %2" : "=v"(d) : "v"(a), "v"(b));
    return d;
}
__device__ __forceinline__ pf2 pk_fma(pf2 a, pf2 b, pf2 c) {
    pf2 d;
    asm("v_pk_fma_f32 %0, %1, %2, %3" : "=v"(d) : "v"(a), "v"(b), "v"(c));
    return d;
}

// ---------------------------------------------------------------------------
// k_pairs v10 == v8 (best measured: 19.83 us). v9's g-elimination reverted —
// DS reads were latency-hidden at 4 waves/SIMD; LDS-stored g is cheaper than
// recomputing it per element.
//
// Structure: 16-lane group per j, two-pass direct v-form, packed fp32.
//   a = x_i/||x_i||, g = 1+a^3 (LDS);  c = 1/max(||b||,eps)  [pass 1]
//   w = b*g: du=S(aw), uu=S(w^2);  p=a*b, q=p^2, v=c*q+b: dv=S(av), vv=S(v^2)
//   ds = du/max(sqrt(uu),eps)/T;   dn = dv/max(sqrt(vv),eps)/T
// Partials per (i,jg): sum_j ds, sum_j (e^ds + 3 e^dn).
// ---------------------------------------------------------------------------
__global__ __launch_bounds__(256, 4) void k_pairs(const float* __restrict__ feat,
                                                  float* __restrict__ part) {
    const int blk = blockIdx.x;
    const int i = blk >> 3;
    const int jg = blk & 7;
    const int tid = threadIdx.x;
    const int wave = tid >> 6, lane = tid & 63;
    const int s = lane & 15;      // sublane within 16-lane group
    const int grp = lane >> 4;    // group 0..3 -> which j

    __shared__ float sa[K_];
    __shared__ float sg[K_];
    __shared__ float wsum[4];

    // ---- stage i-row: block-local norm, then a and g=1+a^3 into LDS ----
    {
        const float4* fi4 = reinterpret_cast<const float4*>(feat + (size_t)i * K_);
        float4 v0 = fi4[tid];
        float4 v1 = fi4[tid + 256];
        float ss = v0.x * v0.x + v0.y * v0.y + v0.z * v0.z + v0.w * v0.w
                 + v1.x * v1.x + v1.y * v1.y + v1.z * v1.z + v1.w * v1.w;
#pragma unroll
        for (int o = 1; o < 64; o <<= 1) ss += __shfl_xor(ss, o, 64);
        if (lane == 0) wsum[wave] = ss;
        __syncthreads();
        const float tot = wsum[0] + wsum[1] + wsum[2] + wsum[3];
        const float rn = 1.0f / fmaxf(sqrtf(tot), EPS_);

        float4* a4w = reinterpret_cast<float4*>(sa);
        float4* g4w = reinterpret_cast<float4*>(sg);
#define STAGE(V, IDX)                                                   \
        {                                                               \
            float4 a, g;                                                \
            a.x = (V).x * rn; a.y = (V).y * rn;                         \
            a.z = (V).z * rn; a.w = (V).w * rn;                         \
            g.x = 1.0f + a.x * a.x * a.x; g.y = 1.0f + a.y * a.y * a.y; \
            g.z = 1.0f + a.z * a.z * a.z; g.w = 1.0f + a.w * a.w * a.w; \
            a4w[IDX] = a; g4w[IDX] = g;                                 \
        }
        STAGE(v0, tid)
        STAGE(v1, tid + 256)
#undef STAGE
    }
    __syncthreads();

    const int j = jg * 16 + wave * 4 + grp;
    const float4* bj = reinterpret_cast<const float4*>(feat + (size_t)j * K_);
    const float4* a4 = reinterpret_cast<const float4*>(sa);
    const float4* g4 = reinterpret_cast<const float4*>(sg);

    // ---- pass 1: sbb (packed) ----
    pf2 sbb2 = {0.f, 0.f};
#pragma unroll 8
    for (int c = 0; c < 32; ++c) {
        const float4 b = bj[c * 16 + s];
        pf2 b01; b01.x = b.x; b01.y = b.y;
        pf2 b23; b23.x = b.z; b23.y = b.w;
        sbb2 = pk_fma(b01, b01, sbb2);
        sbb2 = pk_fma(b23, b23, sbb2);
    }
    float sbb = sbb2.x + sbb2.y;
#pragma unroll
    for (int o = 1; o < 16; o <<= 1) sbb += __shfl_xor(sbb, o, 64);
    const float cc = 1.0f / fmaxf(sqrtf(sbb), EPS_);
    pf2 cc2; cc2.x = cc; cc2.y = cc;

    // ---- pass 2: du, uu, dv, vv (packed; v = cc*q + b formed directly) ----
    pf2 du01 = {0.f, 0.f}, du23 = {0.f, 0.f};
    pf2 uu01 = {0.f, 0.f}, uu23 = {0.f, 0.f};
    pf2 dv01 = {0.f, 0.f}, dv23 = {0.f, 0.f};
    pf2 vv01 = {0.f, 0.f}, vv23 = {0.f, 0.f};
#pragma unroll 8
    for (int c = 0; c < 32; ++c) {
        const int idx = c * 16 + s;        // same for all 4 groups: LDS broadcast
        const float4 a = a4[idx];
        const float4 g = g4[idx];
        const float4 b = bj[idx];
        pf2 a01; a01.x = a.x; a01.y = a.y;
        pf2 a23; a23.x = a.z; a23.y = a.w;
        pf2 g01; g01.x = g.x; g01.y = g.y;
        pf2 g23; g23.x = g.z; g23.y = g.w;
        pf2 b01; b01.x = b.x; b01.y = b.y;
        pf2 b23; b23.x = b.z; b23.y = b.w;

        const pf2 w01 = pk_mul(b01, g01);
        const pf2 w23 = pk_mul(b23, g23);
        du01 = pk_fma(a01, w01, du01);
        du23 = pk_fma(a23, w23, du23);
        uu01 = pk_fma(w01, w01, uu01);
        uu23 = pk_fma(w23, w23, uu23);
        const pf2 p01 = pk_mul(a01, b01);
        const pf2 p23 = pk_mul(a23, b23);
        const pf2 q01 = pk_mul(p01, p01);
        const pf2 q23 = pk_mul(p23, p23);
        const pf2 v01 = pk_fma(cc2, q01, b01);
        const pf2 v23 = pk_fma(cc2, q23, b23);
        dv01 = pk_fma(a01, v01, dv01);
        dv23 = pk_fma(a23, v23, dv23);
        vv01 = pk_fma(v01, v01, vv01);
        vv23 = pk_fma(v23, v23, vv23);
    }
    float du = (du01.x + du01.y) + (du23.x + du23.y);
    float uu = (uu01.x + uu01.y) + (uu23.x + uu23.y);
    float dv = (dv01.x + dv01.y) + (dv23.x + dv23.y);
    float vv = (vv01.x + vv01.y) + (vv23.x + vv23.y);

    // ---- 4-step butterfly within the 16-lane group (4 sums) ----
#pragma unroll
    for (int o = 1; o < 16; o <<= 1) {
        du += __shfl_xor(du, o, 64);
        uu += __shfl_xor(uu, o, 64);
        dv += __shfl_xor(dv, o, 64);
        vv += __shfl_xor(vv, o, 64);
    }

    // ---- per-j epilogue ----
    const float inv_t = 1.0f / TEMP_;
    const float ds = du / fmaxf(sqrtf(uu), EPS_) * inv_t;
    const float dn = dv / fmaxf(sqrtf(vv), EPS_) * inv_t;
    float s1 = ds;
    float s2 = __expf(ds) + 3.0f * __expf(dn);

    // ---- combine the wave's 4 j's (cross-group butterfly) ----
    s1 += __shfl_xor(s1, 16, 64); s1 += __shfl_xor(s1, 32, 64);
    s2 += __shfl_xor(s2, 16, 64); s2 += __shfl_xor(s2, 32, 64);

    __shared__ float p1[4], p2[4];
    if (lane == 0) { p1[wave] = s1; p2[wave] = s2; }
    __syncthreads();
    if (tid == 0) {
        part[blk * 2 + 0] = p1[0] + p1[1] + p1[2] + p1[3];
        part[blk * 2 + 1] = p2[0] + p2[1] + p2[2] + p2[3];
    }
}

// ---------------------------------------------------------------------------
// k_final: thread i combines its 8 group-partials, computes
// contrib_i = (1/B) * sum_j d_self - log(denom_i), reduces over i.
// ---------------------------------------------------------------------------
__global__ __launch_bounds__(128) void k_final(const float* __restrict__ part,
                                               float* __restrict__ out) {
    const int i = threadIdx.x;
    float s1 = 0.0f, s2 = 0.0f;
#pragma unroll
    for (int q = 0; q < 8; ++q) {
        s1 += part[(i * 8 + q) * 2 + 0];
        s2 += part[(i * 8 + q) * 2 + 1];
    }
    float c = s1 * (1.0f / B_) - __logf(s2);
#pragma unroll
    for (int o = 1; o < 64; o <<= 1) c += __shfl_xor(c, o, 64);
    __shared__ float wsum[2];
    const int wave = i >> 6, lane = i & 63;
    if (lane == 0) wsum[wave] = c;
    __syncthreads();
    if (i == 0) out[0] = -(wsum[0] + wsum[1]) * (1.0f / B_);
}

extern "C" void kernel_launch(void* const* d_in, const int* in_sizes, int n_in,
                              void* d_out, int out_size, void* d_ws, size_t ws_size,
                              hipStream_t stream) {
    const float* feat = (const float*)d_in[0];
    float* part = (float*)d_ws;              // 1024*2 floats
    float* out = (float*)d_out;

    k_pairs<<<NBLK_, 256, 0, stream>>>(feat, part);
    k_final<<<1, 128, 0, stream>>>(part, out);
}